// Round 2
// baseline (185.776 us; speedup 1.0000x reference)
//
#include <hip/hip_runtime.h>
#include <hip/hip_cooperative_groups.h>
#include <math.h>

namespace cg = cooperative_groups;

// ColBERT pairwise late-interaction score — R11: quarter-split + cooperative
// single launch.
//
// Evidence so far: R9 (grid 128, 1 kernel) -> kernel ~11.3 us. R10 (grid 256
// Lk-halves + finalize kernel) -> combined ~14.7 us, i.e. kernel A did NOT
// shrink: per-block latency chain dominates (chip BW only ~24% utilized), and
// the extra launch cost ~3 us. R11 therefore:
//   - grid = 512 (o x 4 k-quarters): 2 blocks/CU co-resident -> two
//     independent latency chains overlap per CU; 4x shorter staging chain.
//   - finalize merged behind cg::this_grid().sync() (single launch; threadfence
//     for cross-XCD ws visibility). Non-coop 2-kernel fallback kept.
//
// Numerics unchanged from R10: S <= 1 -> alpha*S <= 12 bounded exponent, the
// exp-sum splits exactly across j-quarters; masked j -> exp(-1e30)=0 exactly;
// (sum of 4 partials)==0 iff row fully k-masked -> -inf -> zero per reference.

#define ALPHA 12.0f

constexpr int B_  = 64;
constexpr int LQ  = 32;
constexpr int O_  = 128;
constexpr int LK  = 256;
constexpr int NH  = 4;             // k-quarters
constexpr int LKH = LK / NH;       // 64 j-rows per block
constexpr int D_  = 128;
constexpr int LDH = D_ + 8;        // f16 row stride 136 (272 B), 16B-aligned
constexpr int GRID = O_ * NH;      // 512 blocks

typedef _Float16 half8   __attribute__((ext_vector_type(8)));
typedef _Float16 half4_t __attribute__((ext_vector_type(4)));
typedef float    f32x4   __attribute__((ext_vector_type(4)));

__device__ __forceinline__
void partial_phase(const float* __restrict__ q,       // [B, Lq, D]
                   const float* __restrict__ k,       // [O, Lk, D]
                   const int*  __restrict__ q_mask,   // [B, Lq] 0/1
                   const int*  __restrict__ k_mask,   // [O, Lk] 0/1
                   float* __restrict__ ws)            // [NH][B][O][LQ]
{
    __shared__ _Float16 kl[LKH][LDH];       // 17408 B
    __shared__ _Float16 ql2[2][LQ][LDH];    // 17408 B (pair of q tiles)
    __shared__ float rk[LKH];               // 1/||k_j||
    __shared__ float bjs[LKH];              // 0 or -1e30
    __shared__ float rqa2[2][LQ];           // ALPHA/||q_i||
    __shared__ float part2[2][2][LQ];       // [pair][col-half][row]
    __shared__ int   lbm[B_ + 1];           // [0]=M, [1+m]=live b

    const int o     = blockIdx.x >> 2;
    const int h     = blockIdx.x & 3;
    const int t     = threadIdx.x;
    const int lane  = t & 63;
    const int w     = t >> 6;
    const int row16 = lane & 15;
    const int quad  = lane >> 4;

    // ---- wave 0 ONLY: q_mask scan + ballot; waves 1-3 go straight to k ----
    if (w == 0) {
        const int4* qm4 = (const int4*)q_mask;     // [64][32] ints, lane = b
        int4 mm[8];
        #pragma unroll
        for (int u = 0; u < 8; ++u)
            mm[u] = qm4[lane * 8 + u];
        int any = 0;
        #pragma unroll
        for (int u = 0; u < 8; ++u)
            any |= mm[u].x | mm[u].y | mm[u].z | mm[u].w;
        const bool live = (any == 0);
        unsigned long long mb = __ballot(live);
        if (live) {
            int rank = __popcll(mb & ((1ull << lane) - 1ull));
            lbm[1 + rank] = lane;
        }
        if (lane == 0) lbm[0] = (int)__popcll(mb);
    }

    // ---- all waves: quarter k tile load (32 KB), coalesced float4 ----
    const float4* kg = (const float4*)(k + ((size_t)o * LK + (size_t)h * LKH) * D_);
    float4 kv[8];
    #pragma unroll
    for (int r = 0; r < 8; ++r)
        kv[r] = kg[t + 256 * r];                   // 64 rows x 32 float4
    const int km = (t < LKH) ? k_mask[o * LK + h * LKH + t] : 0;

    #pragma unroll
    for (int r = 0; r < 8; ++r) {
        int idx = t + 256 * r;
        int j = idx >> 5, c4 = idx & 31;
        half4_t hh;
        hh[0] = (_Float16)kv[r].x; hh[1] = (_Float16)kv[r].y;
        hh[2] = (_Float16)kv[r].z; hh[3] = (_Float16)kv[r].w;
        *(half4_t*)&kl[j][c4 * 4] = hh;
    }
    __syncthreads();                               // kl + lbm visible

    const int M = lbm[0];
    if (M > 0) {                                   // block-uniform
        // ---- live b's in pairs; iter 0 overlaps q loads with k norms ----
        int midx = 0;
        bool first = true;
        while (midx < M) {
            const int  b0     = lbm[1 + midx];
            const bool has_b1 = (midx + 1 < M);
            const int  b1     = lbm[1 + (has_b1 ? midx + 1 : midx)];
            midx += 2;

            // issue q[b0], q[b1] global loads FIRST (hide under norms)
            const float4* qg0 = (const float4*)(q + (size_t)b0 * LQ * D_);
            const float4* qg1 = (const float4*)(q + (size_t)b1 * LQ * D_);
            float4 qv0[4], qv1[4];
            #pragma unroll
            for (int r = 0; r < 4; ++r) {
                qv0[r] = qg0[t + 256 * r];
                qv1[r] = qg1[t + 256 * r];
            }

            // k norms + mask bias on iteration 0 (VALU while q in flight)
            if (first) {
                if (t < LKH) {
                    float ss = 0.f;
                    #pragma unroll
                    for (int p = 0; p < 16; ++p) {
                        half8 hh = *(const half8*)&kl[t][p * 8];
                        #pragma unroll
                        for (int e = 0; e < 8; ++e) {
                            float x = (float)hh[e];
                            ss = fmaf(x, x, ss);
                        }
                    }
                    rk[t]  = 1.0f / fmaxf(sqrtf(ss), 1e-12f);
                    bjs[t] = (km != 0) ? -1e30f : 0.0f;
                }
                first = false;
            }

            // convert + stage q pair
            #pragma unroll
            for (int r = 0; r < 4; ++r) {
                int idx = t + 256 * r;             // [32][32] float4
                int i = idx >> 5, c4 = idx & 31;
                half4_t h0, h1;
                h0[0] = (_Float16)qv0[r].x; h0[1] = (_Float16)qv0[r].y;
                h0[2] = (_Float16)qv0[r].z; h0[3] = (_Float16)qv0[r].w;
                h1[0] = (_Float16)qv1[r].x; h1[1] = (_Float16)qv1[r].y;
                h1[2] = (_Float16)qv1[r].z; h1[3] = (_Float16)qv1[r].w;
                *(half4_t*)&ql2[0][i][c4 * 4] = h0;
                *(half4_t*)&ql2[1][i][c4 * 4] = h1;
            }
            __syncthreads();                       // ql2 + rk/bjs visible

            // q norms: t<64 covers both pair members (pb = t>>5, i = t&31)
            if (t < 64) {
                const int pb = t >> 5, i = t & 31;
                float ss = 0.f;
                #pragma unroll
                for (int p = 0; p < 16; ++p) {
                    half8 hh = *(const half8*)&ql2[pb][i][p * 8];
                    #pragma unroll
                    for (int e = 0; e < 8; ++e) {
                        float x = (float)hh[e];
                        ss = fmaf(x, x, ss);
                    }
                }
                rqa2[pb][i] = ALPHA / fmaxf(sqrtf(ss), 1e-12f);
            }
            __syncthreads();

            // MFMA: wave w -> rows [16*(w>>1), +16), cols [(w&1)*32, +32)
            const int i0 = (w >> 1) * 16;
            const int j0 = (w & 1) * 32;

            half8 afrag[2][4];
            #pragma unroll
            for (int pb = 0; pb < 2; ++pb)
                #pragma unroll
                for (int kk = 0; kk < 4; ++kk)
                    afrag[pb][kk] =
                        *(const half8*)&ql2[pb][i0 + row16][kk * 32 + quad * 8];

            float rqv[2][4];
            #pragma unroll
            for (int pb = 0; pb < 2; ++pb)
                #pragma unroll
                for (int rg = 0; rg < 4; ++rg)
                    rqv[pb][rg] = rqa2[pb][i0 + quad * 4 + rg];

            float esum[2][4] = {{0.f,0.f,0.f,0.f},{0.f,0.f,0.f,0.f}};
            #pragma unroll
            for (int c = 0; c < 2; ++c) {
                const int jt = j0 + c * 16;
                f32x4 acc0 = {0.f, 0.f, 0.f, 0.f};
                f32x4 acc1 = {0.f, 0.f, 0.f, 0.f};
                #pragma unroll
                for (int kk = 0; kk < 4; ++kk) {
                    half8 bfrag =
                        *(const half8*)&kl[jt + row16][kk * 32 + quad * 8];
                    acc0 = __builtin_amdgcn_mfma_f32_16x16x32_f16(
                               afrag[0][kk], bfrag, acc0, 0, 0, 0);
                    acc1 = __builtin_amdgcn_mfma_f32_16x16x32_f16(
                               afrag[1][kk], bfrag, acc1, 0, 0, 0);
                }
                // C layout: col = lane&15 (j), row = quad*4+reg (i)
                const float rkj = rk[jt + row16];
                const float bb  = bjs[jt + row16];
                #pragma unroll
                for (int rg = 0; rg < 4; ++rg) {
                    esum[0][rg] += __expf(acc0[rg] * rqv[0][rg] * rkj + bb);
                    esum[1][rg] += __expf(acc1[rg] * rqv[1][rg] * rkj + bb);
                }
            }
            #pragma unroll
            for (int pb = 0; pb < 2; ++pb) {
                #pragma unroll
                for (int rg = 0; rg < 4; ++rg) {
                    float e = esum[pb][rg];
                    e += __shfl_xor(e, 1);
                    e += __shfl_xor(e, 2);
                    e += __shfl_xor(e, 4);
                    e += __shfl_xor(e, 8);
                    esum[pb][rg] = e;
                }
                if (row16 == 0)
                    #pragma unroll
                    for (int rg = 0; rg < 4; ++rg)
                        part2[pb][w & 1][i0 + quad * 4 + rg] = esum[pb][rg];
            }
            __syncthreads();

            // write partial esum for this j-quarter: ws[h][b][o][i]
            if (t < 64) {
                const int pb = t >> 5, i = t & 31;
                if (pb == 0 || has_b1) {
                    const int b = pb ? b1 : b0;
                    const float s = part2[pb][0][i] + part2[pb][1][i];
                    ws[(((size_t)h * B_ + b) * O_ + o) * LQ + i] = s;
                }
            }
            // next-iter ql2/part2 writes gated by the barriers ahead.
        }
    }
}

__device__ __forceinline__
void finalize_phase(const float* __restrict__ ws,      // [NH][B][O][LQ]
                    const int*  __restrict__ q_mask,   // [B, Lq]
                    const float* __restrict__ logit_scale,
                    float* __restrict__ out)           // [B, O]
{
    const int t    = threadIdx.x;
    const int lane = t & 63;
    const int w    = t >> 6;
    const int pb   = lane >> 5;                    // which (b,o) pair of 2
    const int i    = lane & 31;                    // q row

    const float ls     = logit_scale[0];
    const float scale  = fminf(__expf(ls), 100.0f);
    const float inv_ln = 1.0f / (sqrtf((float)(LQ * LK)) + 1e-6f);
    const int   gw     = blockIdx.x * 4 + w;       // global wave id [0,2048)

    #pragma unroll
    for (int it = 0; it < 2; ++it) {
        const int p = it * 4096 + gw * 2 + pb;     // (b,o) index [0,8192)
        const int b = p >> 7;
        const int o = p & 127;

        float s = 0.f;
        #pragma unroll
        for (int hh = 0; hh < NH; ++hh)
            s += ws[(((size_t)hh * B_ + b) * O_ + o) * LQ + i];
        const int qm = q_mask[b * LQ + i];

        const bool  badrow = (s <= 0.f);           // row fully k-masked
        float tot = __logf(fmaxf(s, 1e-38f));
        tot += __shfl_xor(tot, 16);
        tot += __shfl_xor(tot, 8);
        tot += __shfl_xor(tot, 4);
        tot += __shfl_xor(tot, 2);
        tot += __shfl_xor(tot, 1);

        unsigned long long zb = __ballot(badrow);
        unsigned long long qb = __ballot(qm != 0); // any q pad -> row b dead
        if (i == 0) {
            unsigned long long half_mask =
                pb ? 0xFFFFFFFF00000000ull : 0x00000000FFFFFFFFull;
            float res = 0.f;
            if (((zb | qb) & half_mask) == 0ull)
                res = (tot * (1.0f / ALPHA)) * inv_ln * scale;
            out[b * O_ + o] = res;
        }
    }
}

__global__ __launch_bounds__(256, 2)
void colbert_coop_kernel(const float* __restrict__ q,
                         const float* __restrict__ k,
                         const int*  __restrict__ q_mask,
                         const int*  __restrict__ k_mask,
                         const float* __restrict__ logit_scale,
                         float* __restrict__ ws,
                         float* __restrict__ out)
{
    partial_phase(q, k, q_mask, k_mask, ws);
    __threadfence();                               // ws visible device-wide
    cg::this_grid().sync();
    finalize_phase(ws, q_mask, logit_scale, out);
}

// ---- non-cooperative fallback path (same math, two launches) ----
__global__ __launch_bounds__(256, 2)
void colbert_partial_kernel(const float* __restrict__ q,
                            const float* __restrict__ k,
                            const int*  __restrict__ q_mask,
                            const int*  __restrict__ k_mask,
                            float* __restrict__ ws)
{
    partial_phase(q, k, q_mask, k_mask, ws);
}

__global__ __launch_bounds__(256, 2)
void colbert_finalize_kernel(const float* __restrict__ ws,
                             const int*  __restrict__ q_mask,
                             const float* __restrict__ logit_scale,
                             float* __restrict__ out)
{
    finalize_phase(ws, q_mask, logit_scale, out);
}

extern "C" void kernel_launch(void* const* d_in, const int* in_sizes, int n_in,
                              void* d_out, int out_size, void* d_ws, size_t ws_size,
                              hipStream_t stream) {
    const float* q           = (const float*)d_in[0];
    const float* k           = (const float*)d_in[1];
    const int*   q_mask      = (const int*)d_in[2];
    const int*   k_mask      = (const int*)d_in[3];
    const float* logit_scale = (const float*)d_in[4];
    float* out = (float*)d_out;
    float* ws  = (float*)d_ws;                     // needs 4*64*128*32*4 = 4 MB

    void* args[7] = {(void*)&q, (void*)&k, (void*)&q_mask, (void*)&k_mask,
                     (void*)&logit_scale, (void*)&ws, (void*)&out};
    hipError_t e = hipLaunchCooperativeKernel(
        (const void*)colbert_coop_kernel, dim3(GRID), dim3(256),
        args, 0, stream);
    if (e != hipSuccess) {
        // capture-safe fallback: two plain launches
        colbert_partial_kernel<<<GRID, 256, 0, stream>>>(q, k, q_mask, k_mask, ws);
        colbert_finalize_kernel<<<GRID, 256, 0, stream>>>(ws, q_mask, logit_scale, out);
    }
}

// Round 3
// 76.661 us; speedup vs baseline: 2.4233x; 2.4233x over previous
//
#include <hip/hip_runtime.h>
#include <math.h>

// ColBERT pairwise late-interaction score — R12: single launch (grid 128,
// as best-known R9) but 1024 threads/block to collapse the intra-block
// serial chain.
//
// Evidence:
//  - R9  (grid 128 x 256t, 1 launch): best total 75.3 us, kernel ~11.3 us.
//  - R10 (Lk-halves, 2 launches): +3.4 us — partial kernel did NOT shrink ->
//    latency-chain bound, not BW bound; extra dispatch costs ~3 us.
//  - R11 (cooperative grid sync): coop kernel 100 us, VALUBusy 1.7% ->
//    cg::this_grid().sync() spins ~90 us on this chip. Never again.
//
// R12 changes vs R9 (same algorithm, same numerics, same barrier structure):
//  - 16 waves/block: k staging 8 float4/thread (whole 131 KB tile in flight
//    in ~1 HBM round trip), q staging 1 float4/thread.
//  - k-norms: 4 threads/row + 2 shfl_xor (chain 32 fmaf, was 128). NOT in the
//    staging loop (R8's regression was shuffles inside staging).
//  - MFMA phase over 16 waves: i0=(w>>3)*16, j0=(w&7)*32 -> 16 MFMA + 16 expf
//    per wave (was 64+64).
//
// out[b,o] = scale/sqrt(Lq*Lk) * sum_i log(sum_j exp(alpha*qn[b,i].kn[o,j]))/alpha
// Row b exactly zero if any q_mask[b,i] -> only M ~ 2-3 of 64 b's live.
// Numerics: S <= 1 -> alpha*S <= 12, exp never overflows; masked j adds -1e30
// before exp -> exact 0; valid j >= e^-12 so rowsum == 0 iff row fully
// k-masked (-inf -> zero). f16 rounding ~1e-3 vs 5.1e-2 threshold.

#define ALPHA 12.0f

constexpr int B_  = 64;
constexpr int LQ  = 32;
constexpr int O_  = 128;
constexpr int LK  = 256;
constexpr int D_  = 128;
constexpr int LDH = D_ + 8;        // f16 row stride 136 (272 B), 16B-aligned
constexpr int NT  = 1024;          // threads per block (16 waves)

typedef _Float16 half8   __attribute__((ext_vector_type(8)));
typedef _Float16 half4_t __attribute__((ext_vector_type(4)));
typedef float    f32x4   __attribute__((ext_vector_type(4)));

__global__ __launch_bounds__(NT, 4)
void colbert_fused_kernel(const float* __restrict__ q,       // [B, Lq, D]
                          const float* __restrict__ k,       // [O, Lk, D]
                          const int*  __restrict__ q_mask,   // [B, Lq] 0/1
                          const int*  __restrict__ k_mask,   // [O, Lk] 0/1
                          const float* __restrict__ logit_scale,
                          float* __restrict__ out)           // [B, O]
{
    __shared__ _Float16 kl[LK][LDH];        // 69632 B
    __shared__ _Float16 ql2[2][LQ][LDH];    // 17408 B (pair of q tiles)
    __shared__ float rk[LK];                // 1/||k_j||
    __shared__ float bjs[LK];               // 0 or -1e30
    __shared__ float rqa2[2][LQ];           // ALPHA/||q_i||
    __shared__ float part2[2][8][LQ];       // [pair][col-chunk][row]
    __shared__ int   lbm[B_ + 1];           // [0]=M, [1+m]=live b

    const int o     = blockIdx.x;
    const int t     = threadIdx.x;
    const int lane  = t & 63;
    const int w     = t >> 6;
    const int row16 = lane & 15;
    const int quad  = lane >> 4;

    // ---- wave 0 ONLY: q_mask scan + ballot + dead-row zeroing;
    //      waves 1-15 go straight to the k loads ----
    if (w == 0) {
        const int4* qm4 = (const int4*)q_mask;     // [64][32] ints, lane = b
        int4 mm[8];
        #pragma unroll
        for (int u = 0; u < 8; ++u)
            mm[u] = qm4[lane * 8 + u];
        int any = 0;
        #pragma unroll
        for (int u = 0; u < 8; ++u)
            any |= mm[u].x | mm[u].y | mm[u].z | mm[u].w;
        const bool live = (any == 0);
        unsigned long long mb = __ballot(live);
        if (live) {
            int rank = __popcll(mb & ((1ull << lane) - 1ull));
            lbm[1 + rank] = lane;
        } else {
            out[lane * O_ + o] = 0.0f;             // dead row -> exact zero
        }
        if (lane == 0) lbm[0] = (int)__popcll(mb);
    }

    // k_mask for this thread's norm row (issued alongside k tile loads)
    const int jrow = t >> 2;                       // 4 threads per k row
    const int jprt = t & 3;
    const int km   = (jprt == 0) ? k_mask[o * LK + jrow] : 0;
    const float ls = logit_scale[0];

    // ---- all waves: k tile load (131 KB), 8 float4/thread, coalesced ----
    const float4* kg = (const float4*)(k + (size_t)o * LK * D_);
    float4 kv[8];
    #pragma unroll
    for (int r = 0; r < 8; ++r)
        kv[r] = kg[t + NT * r];
    #pragma unroll
    for (int r = 0; r < 8; ++r) {
        int idx = t + NT * r;                      // float4 index
        int j = idx >> 5, c4 = idx & 31;
        half4_t hh;
        hh[0] = (_Float16)kv[r].x; hh[1] = (_Float16)kv[r].y;
        hh[2] = (_Float16)kv[r].z; hh[3] = (_Float16)kv[r].w;
        *(half4_t*)&kl[j][c4 * 4] = hh;
    }
    __syncthreads();                               // kl + lbm visible

    const int M = lbm[0];
    if (M == 0) return;                            // block-uniform

    const float scale  = fminf(__expf(ls), 100.0f);
    const float inv_ln = 1.0f / (sqrtf((float)(LQ * LK)) + 1e-6f);

    // ---- live b's in pairs; iteration 0 overlaps q loads with k norms ----
    int midx = 0;
    bool first = true;
    while (midx < M) {
        const int b0 = lbm[1 + midx];
        const int b1 = lbm[1 + ((midx + 1 < M) ? midx + 1 : midx)];
        midx += 2;

        // issue q[b0], q[b1] global loads FIRST (latency hides under norms)
        const float4* qg0 = (const float4*)(q + (size_t)b0 * LQ * D_);
        const float4* qg1 = (const float4*)(q + (size_t)b1 * LQ * D_);
        float4 qv0 = qg0[t];                       // 1 float4 per member
        float4 qv1 = qg1[t];

        // k norms + mask bias on iteration 0: 4 threads/row, 2 shfl_xor
        if (first) {
            float ss = 0.f;
            #pragma unroll
            for (int p = 0; p < 4; ++p) {
                half8 hh = *(const half8*)&kl[jrow][jprt * 32 + p * 8];
                #pragma unroll
                for (int e = 0; e < 8; ++e) {
                    float x = (float)hh[e];
                    ss = fmaf(x, x, ss);
                }
            }
            ss += __shfl_xor(ss, 1);
            ss += __shfl_xor(ss, 2);
            if (jprt == 0) {
                rk[jrow]  = 1.0f / fmaxf(sqrtf(ss), 1e-12f);
                bjs[jrow] = (km != 0) ? -1e30f : 0.0f;
            }
            first = false;
        }

        // convert + stage q pair (1 float4 each)
        {
            const int i = t >> 5, c4 = t & 31;     // [32][32] float4
            half4_t h0, h1;
            h0[0] = (_Float16)qv0.x; h0[1] = (_Float16)qv0.y;
            h0[2] = (_Float16)qv0.z; h0[3] = (_Float16)qv0.w;
            h1[0] = (_Float16)qv1.x; h1[1] = (_Float16)qv1.y;
            h1[2] = (_Float16)qv1.z; h1[3] = (_Float16)qv1.w;
            *(half4_t*)&ql2[0][i][c4 * 4] = h0;
            *(half4_t*)&ql2[1][i][c4 * 4] = h1;
        }
        __syncthreads();                           // ql2 + rk/bjs visible

        // q norms: t<64 covers both pair members (pb = t>>5, i = t&31)
        if (t < 64) {
            const int pb = t >> 5, i = t & 31;
            float ss = 0.f;
            #pragma unroll
            for (int p = 0; p < 16; ++p) {
                half8 hh = *(const half8*)&ql2[pb][i][p * 8];
                #pragma unroll
                for (int e = 0; e < 8; ++e) {
                    float x = (float)hh[e];
                    ss = fmaf(x, x, ss);
                }
            }
            rqa2[pb][i] = ALPHA / fmaxf(sqrtf(ss), 1e-12f);
        }
        __syncthreads();

        // MFMA: wave w -> rows [16*(w>>3), +16), cols [(w&7)*32, +32)
        const int i0 = (w >> 3) * 16;
        const int j0 = (w & 7) * 32;

        half8 afrag[2][4];
        #pragma unroll
        for (int pb = 0; pb < 2; ++pb)
            #pragma unroll
            for (int kk = 0; kk < 4; ++kk)
                afrag[pb][kk] =
                    *(const half8*)&ql2[pb][i0 + row16][kk * 32 + quad * 8];

        float rqv[2][4];
        #pragma unroll
        for (int pb = 0; pb < 2; ++pb)
            #pragma unroll
            for (int rg = 0; rg < 4; ++rg)
                rqv[pb][rg] = rqa2[pb][i0 + quad * 4 + rg];

        float esum[2][4] = {{0.f,0.f,0.f,0.f},{0.f,0.f,0.f,0.f}};
        #pragma unroll
        for (int c = 0; c < 2; ++c) {
            const int jt = j0 + c * 16;
            f32x4 acc0 = {0.f, 0.f, 0.f, 0.f};
            f32x4 acc1 = {0.f, 0.f, 0.f, 0.f};
            #pragma unroll
            for (int kk = 0; kk < 4; ++kk) {
                half8 bfrag =
                    *(const half8*)&kl[jt + row16][kk * 32 + quad * 8];
                acc0 = __builtin_amdgcn_mfma_f32_16x16x32_f16(
                           afrag[0][kk], bfrag, acc0, 0, 0, 0);
                acc1 = __builtin_amdgcn_mfma_f32_16x16x32_f16(
                           afrag[1][kk], bfrag, acc1, 0, 0, 0);
            }
            // C layout: col = lane&15 (j), row = quad*4+reg (i)
            const float rkj = rk[jt + row16];
            const float bb  = bjs[jt + row16];
            #pragma unroll
            for (int rg = 0; rg < 4; ++rg) {
                esum[0][rg] += __expf(acc0[rg] * rqv[0][rg] * rkj + bb);
                esum[1][rg] += __expf(acc1[rg] * rqv[1][rg] * rkj + bb);
            }
        }
        #pragma unroll
        for (int pb = 0; pb < 2; ++pb) {
            #pragma unroll
            for (int rg = 0; rg < 4; ++rg) {
                float e = esum[pb][rg];
                e += __shfl_xor(e, 1);
                e += __shfl_xor(e, 2);
                e += __shfl_xor(e, 4);
                e += __shfl_xor(e, 8);
                esum[pb][rg] = e;
            }
            if (row16 == 0)
                #pragma unroll
                for (int rg = 0; rg < 4; ++rg)
                    part2[pb][w & 7][i0 + quad * 4 + rg] = esum[pb][rg];
        }
        __syncthreads();

        // finalize both pair members: wave 0 (b1==b0 double-write benign)
        if (t < 64) {
            const int pb = t >> 5, i = t & 31;
            float s = 0.f;
            #pragma unroll
            for (int cc = 0; cc < 8; ++cc)
                s += part2[pb][cc][i];
            bool badrow = (s <= 0.f);              // row fully k-masked
            float lse = __logf(fmaxf(s, 1e-38f));
            float tot = lse;
            tot += __shfl_xor(tot, 16);
            tot += __shfl_xor(tot, 8);
            tot += __shfl_xor(tot, 4);
            tot += __shfl_xor(tot, 2);
            tot += __shfl_xor(tot, 1);
            unsigned long long zb = __ballot(badrow);
            if (i == 0) {
                unsigned long long half_mask =
                    (pb == 0) ? 0xFFFFFFFFull : 0xFFFFFFFF00000000ull;
                float res = 0.f;
                if ((zb & half_mask) == 0ull)
                    res = (tot * (1.0f / ALPHA)) * inv_ln * scale;
                out[((pb == 0) ? b0 : b1) * O_ + o] = res;
            }
        }
        // next-iter ql2/part2 writes are gated by the barriers ahead — same
        // protection structure as R9.
    }
}

extern "C" void kernel_launch(void* const* d_in, const int* in_sizes, int n_in,
                              void* d_out, int out_size, void* d_ws, size_t ws_size,
                              hipStream_t stream) {
    const float* q           = (const float*)d_in[0];
    const float* k           = (const float*)d_in[1];
    const int*   q_mask      = (const int*)d_in[2];
    const int*   k_mask      = (const int*)d_in[3];
    const float* logit_scale = (const float*)d_in[4];
    float* out = (float*)d_out;

    colbert_fused_kernel<<<O_, NT, 0, stream>>>(q, k, q_mask, k_mask,
                                                logit_scale, out);
}